// Round 16
// baseline (273.240 us; speedup 1.0000x reference)
//
#include <hip/hip_runtime.h>
#include <stdint.h>

typedef uint16_t u16;
typedef __attribute__((ext_vector_type(4))) float f32x4;
typedef __attribute__((ext_vector_type(2))) unsigned short u16x2;
typedef __attribute__((ext_vector_type(4))) unsigned short u16x4;
typedef __attribute__((ext_vector_type(8))) __bf16 bf16x8;

#define HIDDEN 2048
#define LSEQ   2048
#define NH     16
#define HD     128
#define NQK    6144   // 3*HIDDEN, qkv row stride
// 1/sqrt(128) * log2(e): folded into Wq so attn works in exp2 domain
#define QSCALE 0.12751743f
// static softmax max (log2 domain); fallback handles exceedance exactly
#define M0 32.0f

// ---------- bf16 helpers (RNE) ----------
__device__ __forceinline__ u16 f2b(float f) {
  union { float f; uint32_t u; } v; v.f = f;
  uint32_t r = v.u + 0x7fffu + ((v.u >> 16) & 1u);
  return (u16)(r >> 16);
}
__device__ __forceinline__ float b2f(u16 h) {
  union { uint32_t u; float f; } v; v.u = ((uint32_t)h) << 16;
  return v.f;
}

__device__ __forceinline__ void gload16(const void* g, void* l) {
  __builtin_amdgcn_global_load_lds((const __attribute__((address_space(1))) void*)g,
                                   (__attribute__((address_space(3))) void*)l, 16, 0, 0);
}
__device__ __forceinline__ f32x4 mfma16(bf16x8 a, bf16x8 b, f32x4 c) {
  return __builtin_amdgcn_mfma_f32_16x16x32_bf16(a, b, c, 0, 0, 0);
}

// ---------- fused prep: 4 weight transposes + rope table + hidden f32->bf16 ----------
__global__ __launch_bounds__(256) void k_prep(const float* __restrict__ Wq,
                                              const float* __restrict__ Wk,
                                              const float* __restrict__ Wv,
                                              const float* __restrict__ Wo,
                                              u16* __restrict__ WT, u16* __restrict__ WoT,
                                              const int* __restrict__ pos, int pstride,
                                              float* __restrict__ tab,
                                              const float* __restrict__ hidden,
                                              u16* __restrict__ hbf) {
  const int z = blockIdx.z;
  if (z >= 5) {
    int i = (((z - 5) * 1024) + blockIdx.y * 32 + blockIdx.x) * 256 + threadIdx.x;
    if (i >= 2097152) return;                  // 8M elems / 4
    float4 v = ((const float4*)hidden)[i];
    u16x4 o = { f2b(v.x), f2b(v.y), f2b(v.z), f2b(v.w) };
    ((u16x4*)hbf)[i] = o;
    return;
  }
  if (z == 4) {
    int i = (blockIdx.y * 32 + blockIdx.x) * 256 + threadIdx.x;
    if (i >= LSEQ * 64) return;
    int l = i >> 6, j = i & 63;
    float p = (float)pos[(size_t)l * pstride];
    float th = p * expf(-(float)j * 0.14391156642178528f);  // ln(10000)/64
    tab[2 * i + 0] = cosf(th);
    tab[2 * i + 1] = sinf(th);
    return;
  }
  const float* W = (z == 0) ? Wq : (z == 1) ? Wk : (z == 2) ? Wv : Wo;
  u16* D = (z < 3) ? (WT + (size_t)z * HIDDEN * HIDDEN) : WoT;
  const float scale = (z == 0) ? QSCALE : 1.0f;
  const int R = HIDDEN, C = HIDDEN;

  __shared__ u16 tile[64][65];
  const int bx = blockIdx.x, by = blockIdx.y;
  const int t = threadIdx.x;
  const int g = t >> 4, k = t & 15;
#pragma unroll
  for (int p = 0; p < 4; ++p) {
    int r = by * 64 + p * 16 + g;
    int c = bx * 64 + k * 4;
    float4 v = *(const float4*)(W + (size_t)r * C + c);
    tile[p * 16 + g][k * 4 + 0] = f2b(v.x * scale);
    tile[p * 16 + g][k * 4 + 1] = f2b(v.y * scale);
    tile[p * 16 + g][k * 4 + 2] = f2b(v.z * scale);
    tile[p * 16 + g][k * 4 + 3] = f2b(v.w * scale);
  }
  __syncthreads();
#pragma unroll
  for (int p = 0; p < 4; ++p) {
    int n = bx * 64 + p * 16 + g;
    int kk = by * 64 + k * 4;
    u16x4 o = { tile[k * 4 + 0][p * 16 + g], tile[k * 4 + 1][p * 16 + g],
                tile[k * 4 + 2][p * 16 + g], tile[k * 4 + 3][p * 16 + g] };
    *(u16x4*)(D + (size_t)n * R + kk) = o;
  }
}

// ---------- merged rope-apply + V-transpose (disjoint qkv regions) ----------
__global__ __launch_bounds__(256) void k_rope_tv(u16* __restrict__ qkv,
                                                 const float* __restrict__ tab,
                                                 u16* __restrict__ vt) {
  const int bidg = blockIdx.x;
  if (bidg < 2048) {
    __shared__ u16 tile[64][65];
    const int lt = bidg & 31;             // l tile (64)
    const int dt = (bidg >> 5) & 1;       // d tile (64)
    const int bh = bidg >> 6;             // b*16+h
    const int t = threadIdx.x;
    const int g = t >> 4, k = t & 15;
    const u16* src = qkv + (size_t)(bh >> 4) * LSEQ * NQK + 2 * HIDDEN + (bh & 15) * HD;
#pragma unroll
    for (int p = 0; p < 4; ++p) {
      int l = lt * 64 + p * 16 + g;
      int d = dt * 64 + k * 4;
      u16x4 v = *(const u16x4*)(src + (size_t)l * NQK + d);
      tile[p * 16 + g][k * 4 + 0] = v[0];
      tile[p * 16 + g][k * 4 + 1] = v[1];
      tile[p * 16 + g][k * 4 + 2] = v[2];
      tile[p * 16 + g][k * 4 + 3] = v[3];
    }
    __syncthreads();
    u16* dst = vt + (size_t)bh * HD * LSEQ;
#pragma unroll
    for (int p = 0; p < 4; ++p) {
      int d = dt * 64 + p * 16 + g;
      int l = lt * 64 + k * 4;
      u16x4 o = { tile[k * 4 + 0][p * 16 + g], tile[k * 4 + 1][p * 16 + g],
                  tile[k * 4 + 2][p * 16 + g], tile[k * 4 + 3][p * 16 + g] };
      *(u16x4*)(dst + (size_t)d * LSEQ + l) = o;
    }
    return;
  }
  int i = (bidg - 2048) * 256 + threadIdx.x;   // rows(4096) x mat(2) x h(16) x dph(32)
  int dph = i & 31;
  int h = (i >> 5) & 15;
  int mat = (i >> 9) & 1;
  int row = i >> 10;
  int l = row & (LSEQ - 1);
  const float* t1 = tab + 2 * (l * 64 + dph);
  const float* t2 = tab + 2 * (l * 64 + 32 + dph);
  size_t base = (size_t)row * NQK + mat * HIDDEN + h * HD + dph * 2;
  u16x2 xa = *(u16x2*)(qkv + base);
  u16x2 xb = *(u16x2*)(qkv + base + 64);
  float x1a = b2f(xa[0]), x1b = b2f(xa[1]), x2a = b2f(xb[0]), x2b = b2f(xb[1]);
  u16x2 oa = { f2b(t1[0] * x1a - t1[1] * x2a), f2b(t1[0] * x1b - t1[1] * x2b) };
  u16x2 ob = { f2b(t2[0] * x2a + t2[1] * x1a), f2b(t2[0] * x2b + t2[1] * x1b) };
  *(u16x2*)(qkv + base) = oa;
  *(u16x2*)(qkv + base + 64) = ob;
}

// ---------- k_gemm4: QKV GEMM, 256x256 8-phase template (m201 port) ----------
// 8 waves 2Mx4N, per-wave 128x64 (acc[8][4] -> AGPRs). BK=64.
// LDS 128KB: A[2dbuf][2half][128][64] @0, B same @65536. Per K-tile 4 phases:
// {ds_read quadrant ∥ issue 1 half-tile stage of t+1} -> bar -> lgkmcnt(0) ->
// sched_barrier -> setprio(1) 16 MFMA setprio(0) -> bar. Boundary vmcnt(0)
// (loads issued 1-4 phases early, T14 issue-early/wait-late).
// Race-safe: dbuf[(t+1)&1] last read at tile t-1's end (barrier-separated).
__global__ __launch_bounds__(512, 2) void k_gemm4(const u16* __restrict__ A,
                                                  const u16* __restrict__ Bt,
                                                  u16* __restrict__ C,
                                                  int M, int N, int K) {
  __shared__ __align__(16) char lds[131072];
  const int tid = threadIdx.x, w = tid >> 6, lane = tid & 63;
  const int l15 = lane & 15, l4 = lane >> 4;
  const int wm = w >> 2, wn = w & 3;
  // bijective XCD swizzle (nwg % 8 == 0)
  const int nbx = gridDim.x;
  const int nwg = nbx * gridDim.y;
  const int id = blockIdx.y * nbx + blockIdx.x;
  const int qq = nwg >> 3;
  const int sid = (id & 7) * qq + (id >> 3);
  const int bn = sid % nbx, bm = sid / nbx;
  const u16* Ag = A + (size_t)bm * 256 * K;
  const u16* Bg = Bt + (size_t)bn * 256 * K;

  // stage one half-tile (128 rows x 64 k = 16KB): 2 gload16/thread
  auto stageHalf = [&](const u16* G, int kt, int half, int isB) {
    char* dst = lds + (isB ? 65536 : 0) + (kt & 1) * 32768 + half * 16384;
    const int k0 = kt << 6;
#pragma unroll
    for (int i = 0; i < 2; ++i) {
      int c = i * 512 + tid;
      int row = c >> 3, s = (c & 7) ^ (row & 7);
      gload16(G + (size_t)(half * 128 + row) * K + k0 + s * 8, dst + c * 16);
    }
  };

  const int Aoff = wm * 16384;                  // wave's A half
  const int Boff = 65536 + (wn >> 1) * 16384;   // wave's B half
  const int brow0 = (wn & 1) * 64;              // B row base within half

  const int NT = K >> 6;
  stageHalf(Ag, 0, 0, 0); stageHalf(Ag, 0, 1, 0);
  stageHalf(Bg, 0, 0, 1); stageHalf(Bg, 0, 1, 1);
  asm volatile("s_waitcnt vmcnt(0)" ::: "memory");
  __builtin_amdgcn_s_barrier();
  asm volatile("" ::: "memory");

  f32x4 acc[8][4] = {};
  for (int t = 0; t < NT; ++t) {
    const int d = t & 1;
    const char* Ab = lds + d * 32768 + Aoff;
    const char* Bb = lds + d * 32768 + Boff;
    const bool st = (t + 1 < NT);
    auto rdA = [&](int mi, int ks) {            // row&7 == l15&7
      int row = mi * 16 + l15;
      return *(const bf16x8*)(Ab + row * 128 + (((ks * 4 + l4) ^ (l15 & 7)) * 16));
    };
    auto rdB = [&](int nj, int ks) {
      int row = brow0 + nj * 16 + l15;
      return *(const bf16x8*)(Bb + row * 128 + (((ks * 4 + l4) ^ (l15 & 7)) * 16));
    };
    bf16x8 af[4][2], bf01[2][2], bf23[2][2];

    // ---- phase 0: read A mi0-3 + B nj0-1; stage A(t+1) half0; MFMA mi0-3 x nj0-1
#pragma unroll
    for (int mi = 0; mi < 4; ++mi) { af[mi][0] = rdA(mi, 0); af[mi][1] = rdA(mi, 1); }
#pragma unroll
    for (int nj = 0; nj < 2; ++nj) { bf01[nj][0] = rdB(nj, 0); bf01[nj][1] = rdB(nj, 1); }
    if (st) stageHalf(Ag, t + 1, 0, 0);
    __builtin_amdgcn_s_barrier();
    asm volatile("s_waitcnt lgkmcnt(0)" ::: "memory");
    __builtin_amdgcn_sched_barrier(0);
    __builtin_amdgcn_s_setprio(1);
#pragma unroll
    for (int mi = 0; mi < 4; ++mi)
#pragma unroll
      for (int nj = 0; nj < 2; ++nj) {
        acc[mi][nj] = mfma16(af[mi][0], bf01[nj][0], acc[mi][nj]);
        acc[mi][nj] = mfma16(af[mi][1], bf01[nj][1], acc[mi][nj]);
      }
    __builtin_amdgcn_s_setprio(0);
    __builtin_amdgcn_s_barrier();

    // ---- phase 1: read B nj2-3; stage A(t+1) half1; MFMA mi0-3 x nj2-3
#pragma unroll
    for (int nj = 0; nj < 2; ++nj) { bf23[nj][0] = rdB(nj + 2, 0); bf23[nj][1] = rdB(nj + 2, 1); }
    if (st) stageHalf(Ag, t + 1, 1, 0);
    __builtin_amdgcn_s_barrier();
    asm volatile("s_waitcnt lgkmcnt(0)" ::: "memory");
    __builtin_amdgcn_sched_barrier(0);
    __builtin_amdgcn_s_setprio(1);
#pragma unroll
    for (int mi = 0; mi < 4; ++mi)
#pragma unroll
      for (int nj = 0; nj < 2; ++nj) {
        acc[mi][nj + 2] = mfma16(af[mi][0], bf23[nj][0], acc[mi][nj + 2]);
        acc[mi][nj + 2] = mfma16(af[mi][1], bf23[nj][1], acc[mi][nj + 2]);
      }
    __builtin_amdgcn_s_setprio(0);
    __builtin_amdgcn_s_barrier();

    // ---- phase 2: read A mi4-7 (reuse af regs); stage B(t+1) half0; MFMA mi4-7 x nj2-3
#pragma unroll
    for (int mi = 0; mi < 4; ++mi) { af[mi][0] = rdA(mi + 4, 0); af[mi][1] = rdA(mi + 4, 1); }
    if (st) stageHalf(Bg, t + 1, 0, 1);
    __builtin_amdgcn_s_barrier();
    asm volatile("s_waitcnt lgkmcnt(0)" ::: "memory");
    __builtin_amdgcn_sched_barrier(0);
    __builtin_amdgcn_s_setprio(1);
#pragma unroll
    for (int mi = 0; mi < 4; ++mi)
#pragma unroll
      for (int nj = 0; nj < 2; ++nj) {
        acc[mi + 4][nj + 2] = mfma16(af[mi][0], bf23[nj][0], acc[mi + 4][nj + 2]);
        acc[mi + 4][nj + 2] = mfma16(af[mi][1], bf23[nj][1], acc[mi + 4][nj + 2]);
      }
    __builtin_amdgcn_s_setprio(0);
    __builtin_amdgcn_s_barrier();

    // ---- phase 3: stage B(t+1) half1; MFMA mi4-7 x nj0-1; boundary vmcnt(0)
    if (st) stageHalf(Bg, t + 1, 1, 1);
    __builtin_amdgcn_s_barrier();
    __builtin_amdgcn_sched_barrier(0);
    __builtin_amdgcn_s_setprio(1);
#pragma unroll
    for (int mi = 0; mi < 4; ++mi)
#pragma unroll
      for (int nj = 0; nj < 2; ++nj) {
        acc[mi + 4][nj] = mfma16(af[mi][0], bf01[nj][0], acc[mi + 4][nj]);
        acc[mi + 4][nj] = mfma16(af[mi][1], bf01[nj][1], acc[mi + 4][nj]);
      }
    __builtin_amdgcn_s_setprio(0);
    asm volatile("s_waitcnt vmcnt(0)" ::: "memory");   // t+1 halves landed (issued 1-4 phases ago)
    __builtin_amdgcn_s_barrier();
    asm volatile("" ::: "memory");
  }

#pragma unroll
  for (int mi = 0; mi < 8; ++mi) {
#pragma unroll
    for (int nj = 0; nj < 4; ++nj) {
      int row0 = bm * 256 + wm * 128 + mi * 16 + l4 * 4;
      int col  = bn * 256 + wn * 64 + nj * 16 + l15;
#pragma unroll
      for (int r = 0; r < 4; ++r)
        C[(size_t)(row0 + r) * N + col] = f2b(acc[mi][nj][r]);
    }
  }
}

// ---------- k_gemm2: out-proj GEMM (R10 proven, 128x256, f32 out) ----------
template<int BF16OUT>
__global__ __launch_bounds__(512, 2) void k_gemm2(const u16* __restrict__ A,
                                                  const u16* __restrict__ Bt,
                                                  void* __restrict__ Cv,
                                                  int M, int N, int K) {
  __shared__ __align__(16) char lds[147456];   // A: 3x16KB @0, B: 3x32KB @48K
  const int tid = threadIdx.x, w = tid >> 6, lane = tid & 63;
  const int l15 = lane & 15, l4 = lane >> 4;
  const int wm = w >> 2, wn = w & 3;
  const int nbx = gridDim.x;
  const int nwg = nbx * gridDim.y;
  const int id = blockIdx.y * nbx + blockIdx.x;
  const int qq = nwg >> 3;
  const int sid = (id & 7) * qq + (id >> 3);
  const int bn = sid % nbx, bm = sid / nbx;
  const u16* Ag = A + (size_t)bm * 128 * K;
  const u16* Bg = Bt + (size_t)bn * 256 * K;
  const int r7 = (tid >> 3) & 7;
  const int sw0 = ((0 + l4) ^ (l15 & 7)) * 16;
  const int sw1 = ((4 + l4) ^ (l15 & 7)) * 16;

  auto stageA = [&](int kt, int buf) {
    char* dst = lds + buf * 16384;
    const int k0 = kt << 6;
#pragma unroll
    for (int i = 0; i < 2; ++i) {
      int c = i * 512 + tid;
      int row = c >> 3, s = (c & 7) ^ r7;
      gload16(Ag + (size_t)row * K + k0 + s * 8, dst + (i * 512 + w * 64) * 16);
    }
  };
  auto stageBh = [&](int kt, int buf, int half) {
    char* dst = lds + 49152 + buf * 32768;
    const int k0 = kt << 6;
#pragma unroll
    for (int i = 0; i < 2; ++i) {
      int c = half * 1024 + i * 512 + tid;
      int row = c >> 3, s = (c & 7) ^ r7;
      gload16(Bg + (size_t)row * K + k0 + s * 8, dst + (half * 1024 + i * 512 + w * 64) * 16);
    }
  };

  const int NT = K >> 6;
  stageA(0, 0); stageBh(0, 0, 0); stageBh(0, 0, 1);
  stageA(1, 1); stageBh(1, 1, 0); stageBh(1, 1, 1);
  asm volatile("s_waitcnt vmcnt(6)" ::: "memory");
  __builtin_amdgcn_s_barrier();
  asm volatile("" ::: "memory");

  f32x4 acc[4][4] = {};
  int buf = 0, sbuf = 2;
  for (int t = 0; t < NT; ++t) {
    const char* Ab = lds + buf * 16384;
    const char* Bb = lds + 49152 + buf * 32768;
    const bool doStage = (t + 2 < NT);
    bf16x8 af[4][2], bfr[4][2];
    auto rdA = [&](int mi, int ks) {
      return *(const bf16x8*)(Ab + ((wm * 64 + mi * 16 + l15) << 7) + (ks ? sw1 : sw0));
    };
    auto rdB = [&](int nj, int ks) {
      return *(const bf16x8*)(Bb + ((wn * 64 + nj * 16 + l15) << 7) + (ks ? sw1 : sw0));
    };

#pragma unroll
    for (int mi = 0; mi < 2; ++mi) { af[mi][0] = rdA(mi, 0); af[mi][1] = rdA(mi, 1); }
#pragma unroll
    for (int nj = 0; nj < 2; ++nj) { bfr[nj][0] = rdB(nj, 0); bfr[nj][1] = rdB(nj, 1); }
    if (doStage) stageA(t + 2, sbuf);
    __builtin_amdgcn_s_setprio(1);
#pragma unroll
    for (int mi = 0; mi < 2; ++mi)
#pragma unroll
      for (int nj = 0; nj < 2; ++nj) {
        acc[mi][nj] = mfma16(af[mi][0], bfr[nj][0], acc[mi][nj]);
        acc[mi][nj] = mfma16(af[mi][1], bfr[nj][1], acc[mi][nj]);
      }
    __builtin_amdgcn_s_setprio(0);

#pragma unroll
    for (int nj = 2; nj < 4; ++nj) { bfr[nj][0] = rdB(nj, 0); bfr[nj][1] = rdB(nj, 1); }
    if (doStage) stageBh(t + 2, sbuf, 0);
    __builtin_amdgcn_s_setprio(1);
#pragma unroll
    for (int mi = 0; mi < 2; ++mi)
#pragma unroll
      for (int nj = 2; nj < 4; ++nj) {
        acc[mi][nj] = mfma16(af[mi][0], bfr[nj][0], acc[mi][nj]);
        acc[mi][nj] = mfma16(af[mi][1], bfr[nj][1], acc[mi][nj]);
      }
    __builtin_amdgcn_s_setprio(0);

#pragma unroll
    for (int mi = 2; mi < 4; ++mi) { af[mi][0] = rdA(mi, 0); af[mi][1] = rdA(mi, 1); }
    if (doStage) stageBh(t + 2, sbuf, 1);
    __builtin_amdgcn_s_setprio(1);
#pragma unroll
    for (int mi = 2; mi < 4; ++mi)
#pragma unroll
      for (int nj = 2; nj < 4; ++nj) {
        acc[mi][nj] = mfma16(af[mi][0], bfr[nj][0], acc[mi][nj]);
        acc[mi][nj] = mfma16(af[mi][1], bfr[nj][1], acc[mi][nj]);
      }
    __builtin_amdgcn_s_setprio(0);

    __builtin_amdgcn_s_setprio(1);
#pragma unroll
    for (int mi = 2; mi < 4; ++mi)
#pragma unroll
      for (int nj = 0; nj < 2; ++nj) {
        acc[mi][nj] = mfma16(af[mi][0], bfr[nj][0], acc[mi][nj]);
        acc[mi][nj] = mfma16(af[mi][1], bfr[nj][1], acc[mi][nj]);
      }
    __builtin_amdgcn_s_setprio(0);

    if (doStage) asm volatile("s_waitcnt vmcnt(6)" ::: "memory");
    else         asm volatile("s_waitcnt vmcnt(0)" ::: "memory");
    __builtin_amdgcn_s_barrier();
    asm volatile("" ::: "memory");
    buf = (buf == 2) ? 0 : buf + 1;
    sbuf = (sbuf == 2) ? 0 : sbuf + 1;
  }

#pragma unroll
  for (int mi = 0; mi < 4; ++mi) {
#pragma unroll
    for (int nj = 0; nj < 4; ++nj) {
      int row0 = bm * 128 + wm * 64 + mi * 16 + l4 * 4;
      int col  = bn * 256 + wn * 64 + nj * 16 + l15;
#pragma unroll
      for (int r = 0; r < 4; ++r) {
        float v = acc[mi][nj][r];
        if (BF16OUT) ((u16*)Cv)[(size_t)(row0 + r) * N + col] = f2b(v);
        else         ((float*)Cv)[(size_t)(row0 + r) * N + col] = v;
      }
    }
  }
}

// ---------- flash attention (R15: 80KB LDS, 2 blocks/CU, R7 body) ----------
__global__ __launch_bounds__(512, 2) void k_attn(const u16* __restrict__ qkv,
                                                 const u16* __restrict__ vt,
                                                 u16* __restrict__ aout) {
  __shared__ __align__(16) u16 Ks[2][64 * 128];    // [kv][d], XOR-swizzled rows
  __shared__ __align__(16) u16 Vs[2][128 * 64];    // V^T [d][kv], XOR-swizzled rows
  __shared__ __align__(16) u16 Ps[8 * 16 * 64];    // per-wave P, stride 64, shared A/B
  const int bid = blockIdx.x;                      // 256 blocks
  const int bh = bid & 31, pairi = bid >> 5;       // XCD = bid&7 = bh&7
  const int b = bh >> 4, h = bh & 15;
  const int qtA = pairi, qtB = 15 - pairi;
  const int tid = threadIdx.x, w = tid >> 6, lane = tid & 63;
  const int l15 = lane & 15, l4 = lane >> 4;

  bf16x8 qfA[4], qfB[4];
  {
    const u16* qpA = qkv + (size_t)(b * LSEQ + qtA * 128 + w * 16 + l15) * NQK + h * HD;
    const u16* qpB = qkv + (size_t)(b * LSEQ + qtB * 128 + w * 16 + l15) * NQK + h * HD;
#pragma unroll
    for (int ks = 0; ks < 4; ++ks) {
      qfA[ks] = *(const bf16x8*)(qpA + ks * 32 + l4 * 8);
      qfB[ks] = *(const bf16x8*)(qpB + ks * 32 + l4 * 8);
    }
  }

  f32x4 accA[8] = {}, accB[8] = {};
  float mA[4], lA[4], mB[4], lB[4];
#pragma unroll
  for (int r = 0; r < 4; ++r) { mA[r] = M0; lA[r] = 0.f; mB[r] = M0; lB[r] = 0.f; }

  const u16* kb  = qkv + (size_t)b * LSEQ * NQK + HIDDEN + h * HD;
  const u16* vtb = vt + (size_t)bh * HD * LSEQ;
  const int ntA = 2 * qtA + 2, ntB = 2 * qtB + 2;
  const int qbaseA = qtA * 128 + w * 16, qbaseB = qtB * 128 + w * 16;

  auto stage = [&](int t, int bf) {
    const int kv0 = t * 64;
    char* Kd = (char*)(&Ks[bf][0]);
    char* Vd = (char*)(&Vs[bf][0]);
#pragma unroll
    for (int p = 0; p < 2; ++p) {
      int cc = p * 512 + tid;
      int row = cc >> 4, sl = cc & 15;
      gload16(kb + (size_t)(kv0 + row) * NQK + ((sl ^ (row & 7)) * 8), Kd + (p * 512 + w * 64) * 16);
    }
#pragma unroll
    for (int p = 0; p < 2; ++p) {
      int cc = p * 512 + tid;
      int d = cc >> 3, sl = cc & 7;
      gload16(vtb + (size_t)d * LSEQ + kv0 + ((sl ^ (d & 7)) * 8), Vd + (p * 512 + w * 64) * 16);
    }
  };

  auto tileCompute = [&](const bf16x8 (&qf)[4], f32x4 (&acc_o)[8], float (&mrun)[4],
                         float (&lrun)[4], int qbase, int kv0,
                         const char* KsC, const char* VsC, u16* ps) {
    f32x4 s4[4] = {};
    __builtin_amdgcn_s_setprio(1);
#pragma unroll
    for (int ks = 0; ks < 4; ++ks) {
#pragma unroll
      for (int nj = 0; nj < 4; ++nj) {
        int row = nj * 16 + l15;
        int co = (ks * 64 + l4 * 16) ^ ((row & 7) << 4);
        bf16x8 kf = *(const bf16x8*)(KsC + row * 256 + co);
        s4[nj] = mfma16(qf[ks], kf, s4[nj]);
      }
    }
    __builtin_amdgcn_s_setprio(0);

    const int qrow0 = qbase + l4 * 4;
    float pv[4][4], lm[4];
    if (kv0 + 63 <= qbase) {                     // interior tile: no masking
#pragma unroll
      for (int r = 0; r < 4; ++r) {
        lm[r] = fmaxf(fmaxf(s4[0][r], s4[1][r]), fmaxf(s4[2][r], s4[3][r]));
#pragma unroll
        for (int nj = 0; nj < 4; ++nj) pv[nj][r] = s4[nj][r];
      }
    } else {
#pragma unroll
      for (int r = 0; r < 4; ++r) {
        float mx = -3e38f;
#pragma unroll
        for (int nj = 0; nj < 4; ++nj) {
          int kvcol = kv0 + nj * 16 + l15;
          float sv = (kvcol <= qrow0 + r) ? s4[nj][r] : -3e38f;
          pv[nj][r] = sv;
          mx = fmaxf(mx, sv);
        }
        lm[r] = mx;
      }
    }
    int over = (lm[0] > mrun[0]) | (lm[1] > mrun[1]) | (lm[2] > mrun[2]) | (lm[3] > mrun[3]);
    if (__builtin_expect(__any(over), 0)) {      // exact fallback (rare)
#pragma unroll
      for (int r = 0; r < 4; ++r) {
        float px = lm[r];
        px = fmaxf(px, __shfl_xor(px, 1));
        px = fmaxf(px, __shfl_xor(px, 2));
        px = fmaxf(px, __shfl_xor(px, 4));
        px = fmaxf(px, __shfl_xor(px, 8));
        if (px > mrun[r]) {
          float cf = exp2f(mrun[r] - px);
          mrun[r] = px;
          lrun[r] *= cf;
#pragma unroll
          for (int df = 0; df < 8; ++df) acc_o[df][r] *= cf;
        }
      }
    }
#pragma unroll
    for (int r = 0; r < 4; ++r) {
      float s = 0.f;
#pragma unroll
      for (int nj = 0; nj < 4; ++nj) {
        float e = exp2f(pv[nj][r] - mrun[r]);
        pv[nj][r] = e;
        s += e;
      }
      lrun[r] += s;                              // per-lane partial; reduced at end
    }
#pragma unroll
    for (int nj = 0; nj < 4; ++nj)
#pragma unroll
      for (int r = 0; r < 4; ++r)
        ps[(w * 16 + l4 * 4 + r) * 64 + nj * 16 + l15] = f2b(pv[nj][r]);

    bf16x8 pa[2];
#pragma unroll
    for (int ks2 = 0; ks2 < 2; ++ks2)
      pa[ks2] = *(const bf16x8*)(ps + (w * 16 + l15) * 64 + ks2 * 32 + l4 * 8);
    __builtin_amdgcn_s_setprio(1);
#pragma unroll
    for (int df = 0; df < 8; ++df) {
#pragma unroll
      for (int ks2 = 0; ks2 < 2; ++ks2) {
        int vrow = df * 16 + l15;
        int co = (ks2 * 64 + l4 * 16) ^ ((vrow & 7) << 4);
        bf16x8 bv = *(const bf16x8*)(VsC + vrow * 128 + co);
        acc_o[df] = mfma16(pa[ks2], bv, acc_o[df]);
      }
    }
    __builtin_amdgcn_s_setprio(0);
  };

  stage(0, 0);
  asm volatile("s_waitcnt vmcnt(0)" ::: "memory");
  __builtin_amdgcn_s_barrier();

  for (int t = 0; t < ntB; ++t) {
    const int buf = t & 1;
    if (t + 1 < ntB) stage(t + 1, buf ^ 1);      // prefetch next tile (other buffer)
    const int kv0 = t * 64;
    const char* KsC = (const char*)(&Ks[buf][0]);
    const char* VsC = (const char*)(&Vs[buf][0]);

    if ((t < ntA) && (kv0 <= qbaseA + 15))
      tileCompute(qfA, accA, mA, lA, qbaseA, kv0, KsC, VsC, &Ps[0]);
    if (kv0 <= qbaseB + 15)
      tileCompute(qfB, accB, mB, lB, qbaseB, kv0, KsC, VsC, &Ps[0]);

    asm volatile("s_waitcnt vmcnt(0)" ::: "memory");  // own prefetch landed
    __builtin_amdgcn_s_barrier();
  }

  // epilogue: reduce per-lane partial l across the 16-lane row group, O /= l
#pragma unroll
  for (int r = 0; r < 4; ++r) {
    float sA = lA[r];
    sA += __shfl_xor(sA, 1); sA += __shfl_xor(sA, 2);
    sA += __shfl_xor(sA, 4); sA += __shfl_xor(sA, 8);
    float sB = lB[r];
    sB += __shfl_xor(sB, 1); sB += __shfl_xor(sB, 2);
    sB += __shfl_xor(sB, 4); sB += __shfl_xor(sB, 8);
    float invA = 1.f / sA;
    float invB = 1.f / sB;
    u16* opA = aout + (size_t)(b * LSEQ + qtA * 128 + w * 16 + l4 * 4 + r) * HIDDEN + h * HD;
    u16* opB = aout + (size_t)(b * LSEQ + qtB * 128 + w * 16 + l4 * 4 + r) * HIDDEN + h * HD;
#pragma unroll
    for (int df = 0; df < 8; ++df) {
      opA[df * 16 + l15] = f2b(accA[df][r] * invA);
      opB[df * 16 + l15] = f2b(accB[df][r] * invB);
    }
  }
}

extern "C" void kernel_launch(void* const* d_in, const int* in_sizes, int n_in,
                              void* d_out, int out_size, void* d_ws, size_t ws_size,
                              hipStream_t stream) {
  const float* hidden = (const float*)d_in[0];
  // d_in[1] = attention_mask: causal, applied analytically in k_attn
  const int*   pos = (const int*)d_in[2];
  const float* Wq = (const float*)d_in[3];
  const float* Wk = (const float*)d_in[4];
  const float* Wv = (const float*)d_in[5];
  const float* Wo = (const float*)d_in[6];
  float* out = (float*)d_out;

  char* ws = (char*)d_ws;
  u16* hbf   = (u16*)ws;                                  // [4096][2048] bf16 (reused as attn_out)
  u16* WT    = (u16*)(ws + 16777216);                     // [6144][2048] bf16 (dead after QKV GEMM)
  u16* vt    = WT;                                        // [32][128][2048] bf16 V^T (aliases WT)
  u16* WoT   = (u16*)(ws + 16777216 + 25165824);          // [2048][2048] bf16
  u16* qkv   = (u16*)(ws + 50331648);                     // [4096][6144] bf16
  float* tab = (float*)(ws + 100663296);                  // [2048][64] {cos,sin}
  u16* aout  = hbf;

  int pstride = (in_sizes[2] == LSEQ) ? 1 : 2;            // int32 vs int64-as-int-pairs

  k_prep<<<dim3(32, 32, 13), 256, 0, stream>>>(Wq, Wk, Wv, Wo, WT, WoT, pos, pstride,
                                               tab, hidden, hbf);
  k_gemm4<<<dim3(24, 16), 512, 0, stream>>>(hbf, WT, qkv, 4096, 6144, 2048);
  k_rope_tv<<<18432, 256, 0, stream>>>(qkv, tab, vt);
  k_attn<<<256, 512, 0, stream>>>(qkv, vt, aout);
  k_gemm2<0><<<dim3(8, 32), 512, 0, stream>>>(aout, WoT, out, 4096, 2048, 2048);
}

// Round 17
// 252.428 us; speedup vs baseline: 1.0824x; 1.0824x over previous
//
#include <hip/hip_runtime.h>
#include <stdint.h>

typedef uint16_t u16;
typedef __attribute__((ext_vector_type(4))) float f32x4;
typedef __attribute__((ext_vector_type(2))) unsigned short u16x2;
typedef __attribute__((ext_vector_type(4))) unsigned short u16x4;
typedef __attribute__((ext_vector_type(8))) __bf16 bf16x8;

#define HIDDEN 2048
#define LSEQ   2048
#define NH     16
#define HD     128
#define NQK    6144   // 3*HIDDEN, qkv row stride
// 1/sqrt(128) * log2(e): folded into Wq so attn works in exp2 domain
#define QSCALE 0.12751743f
// static softmax max (log2 domain); fallback handles exceedance exactly
#define M0 32.0f

// ---------- bf16 helpers (RNE) ----------
__device__ __forceinline__ u16 f2b(float f) {
  union { float f; uint32_t u; } v; v.f = f;
  uint32_t r = v.u + 0x7fffu + ((v.u >> 16) & 1u);
  return (u16)(r >> 16);
}
__device__ __forceinline__ float b2f(u16 h) {
  union { uint32_t u; float f; } v; v.u = ((uint32_t)h) << 16;
  return v.f;
}

__device__ __forceinline__ void gload16(const void* g, void* l) {
  __builtin_amdgcn_global_load_lds((const __attribute__((address_space(1))) void*)g,
                                   (__attribute__((address_space(3))) void*)l, 16, 0, 0);
}
__device__ __forceinline__ f32x4 mfma16(bf16x8 a, bf16x8 b, f32x4 c) {
  return __builtin_amdgcn_mfma_f32_16x16x32_bf16(a, b, c, 0, 0, 0);
}

// ---------- fused prep: 4 weight transposes + rope table + hidden f32->bf16 ----------
__global__ __launch_bounds__(256) void k_prep(const float* __restrict__ Wq,
                                              const float* __restrict__ Wk,
                                              const float* __restrict__ Wv,
                                              const float* __restrict__ Wo,
                                              u16* __restrict__ WT, u16* __restrict__ WoT,
                                              const int* __restrict__ pos, int pstride,
                                              float* __restrict__ tab,
                                              const float* __restrict__ hidden,
                                              u16* __restrict__ hbf) {
  const int z = blockIdx.z;
  if (z >= 5) {
    int i = (((z - 5) * 1024) + blockIdx.y * 32 + blockIdx.x) * 256 + threadIdx.x;
    if (i >= 2097152) return;                  // 8M elems / 4
    float4 v = ((const float4*)hidden)[i];
    u16x4 o = { f2b(v.x), f2b(v.y), f2b(v.z), f2b(v.w) };
    ((u16x4*)hbf)[i] = o;
    return;
  }
  if (z == 4) {
    int i = (blockIdx.y * 32 + blockIdx.x) * 256 + threadIdx.x;
    if (i >= LSEQ * 64) return;
    int l = i >> 6, j = i & 63;
    float p = (float)pos[(size_t)l * pstride];
    float th = p * expf(-(float)j * 0.14391156642178528f);  // ln(10000)/64
    tab[2 * i + 0] = cosf(th);
    tab[2 * i + 1] = sinf(th);
    return;
  }
  const float* W = (z == 0) ? Wq : (z == 1) ? Wk : (z == 2) ? Wv : Wo;
  u16* D = (z < 3) ? (WT + (size_t)z * HIDDEN * HIDDEN) : WoT;
  const float scale = (z == 0) ? QSCALE : 1.0f;
  const int R = HIDDEN, C = HIDDEN;

  __shared__ u16 tile[64][65];
  const int bx = blockIdx.x, by = blockIdx.y;
  const int t = threadIdx.x;
  const int g = t >> 4, k = t & 15;
#pragma unroll
  for (int p = 0; p < 4; ++p) {
    int r = by * 64 + p * 16 + g;
    int c = bx * 64 + k * 4;
    float4 v = *(const float4*)(W + (size_t)r * C + c);
    tile[p * 16 + g][k * 4 + 0] = f2b(v.x * scale);
    tile[p * 16 + g][k * 4 + 1] = f2b(v.y * scale);
    tile[p * 16 + g][k * 4 + 2] = f2b(v.z * scale);
    tile[p * 16 + g][k * 4 + 3] = f2b(v.w * scale);
  }
  __syncthreads();
#pragma unroll
  for (int p = 0; p < 4; ++p) {
    int n = bx * 64 + p * 16 + g;
    int kk = by * 64 + k * 4;
    u16x4 o = { tile[k * 4 + 0][p * 16 + g], tile[k * 4 + 1][p * 16 + g],
                tile[k * 4 + 2][p * 16 + g], tile[k * 4 + 3][p * 16 + g] };
    *(u16x4*)(D + (size_t)n * R + kk) = o;
  }
}

// ---------- merged rope-apply + V-transpose (disjoint qkv regions) ----------
__global__ __launch_bounds__(256) void k_rope_tv(u16* __restrict__ qkv,
                                                 const float* __restrict__ tab,
                                                 u16* __restrict__ vt) {
  const int bidg = blockIdx.x;
  if (bidg < 2048) {
    __shared__ u16 tile[64][65];
    const int lt = bidg & 31;             // l tile (64)
    const int dt = (bidg >> 5) & 1;       // d tile (64)
    const int bh = bidg >> 6;             // b*16+h
    const int t = threadIdx.x;
    const int g = t >> 4, k = t & 15;
    const u16* src = qkv + (size_t)(bh >> 4) * LSEQ * NQK + 2 * HIDDEN + (bh & 15) * HD;
#pragma unroll
    for (int p = 0; p < 4; ++p) {
      int l = lt * 64 + p * 16 + g;
      int d = dt * 64 + k * 4;
      u16x4 v = *(const u16x4*)(src + (size_t)l * NQK + d);
      tile[p * 16 + g][k * 4 + 0] = v[0];
      tile[p * 16 + g][k * 4 + 1] = v[1];
      tile[p * 16 + g][k * 4 + 2] = v[2];
      tile[p * 16 + g][k * 4 + 3] = v[3];
    }
    __syncthreads();
    u16* dst = vt + (size_t)bh * HD * LSEQ;
#pragma unroll
    for (int p = 0; p < 4; ++p) {
      int d = dt * 64 + p * 16 + g;
      int l = lt * 64 + k * 4;
      u16x4 o = { tile[k * 4 + 0][p * 16 + g], tile[k * 4 + 1][p * 16 + g],
                  tile[k * 4 + 2][p * 16 + g], tile[k * 4 + 3][p * 16 + g] };
      *(u16x4*)(dst + (size_t)d * LSEQ + l) = o;
    }
    return;
  }
  int i = (bidg - 2048) * 256 + threadIdx.x;   // rows(4096) x mat(2) x h(16) x dph(32)
  int dph = i & 31;
  int h = (i >> 5) & 15;
  int mat = (i >> 9) & 1;
  int row = i >> 10;
  int l = row & (LSEQ - 1);
  const float* t1 = tab + 2 * (l * 64 + dph);
  const float* t2 = tab + 2 * (l * 64 + 32 + dph);
  size_t base = (size_t)row * NQK + mat * HIDDEN + h * HD + dph * 2;
  u16x2 xa = *(u16x2*)(qkv + base);
  u16x2 xb = *(u16x2*)(qkv + base + 64);
  float x1a = b2f(xa[0]), x1b = b2f(xa[1]), x2a = b2f(xb[0]), x2b = b2f(xb[1]);
  u16x2 oa = { f2b(t1[0] * x1a - t1[1] * x2a), f2b(t1[0] * x1b - t1[1] * x2b) };
  u16x2 ob = { f2b(t2[0] * x2a + t2[1] * x1a), f2b(t2[0] * x2b + t2[1] * x1b) };
  *(u16x2*)(qkv + base) = oa;
  *(u16x2*)(qkv + base + 64) = ob;
}

// ---------- k_gemm3: QKV GEMM, BM=128 BN=384 BK=64 (R14/R15 proven) ----------
__global__ __launch_bounds__(512, 2) void k_gemm3(const u16* __restrict__ A,
                                                  const u16* __restrict__ Bt,
                                                  u16* __restrict__ C,
                                                  int M, int N, int K) {
  __shared__ __align__(16) char lds[147456];   // A: 3x16KB @0, B: 2x48KB @48K
  const int tid = threadIdx.x, w = tid >> 6, lane = tid & 63;
  const int l15 = lane & 15, l4 = lane >> 4;
  const int wm = w >> 2, wn = w & 3;
  const int nbx = gridDim.x;
  const int nwg = nbx * gridDim.y;
  const int id = blockIdx.y * nbx + blockIdx.x;
  const int qq = nwg >> 3;
  const int sid = (id & 7) * qq + (id >> 3);
  const int bn = sid % nbx, bm = sid / nbx;
  const u16* Ag = A + (size_t)bm * 128 * K;
  const u16* Bg = Bt + (size_t)bn * 384 * K;
  const int r7 = (tid >> 3) & 7;
  const int sw0 = ((0 + l4) ^ (l15 & 7)) * 16;
  const int sw1 = ((4 + l4) ^ (l15 & 7)) * 16;

  auto stageA = [&](int kt, int buf) {           // 2 loads/thread
    char* dst = lds + buf * 16384;
    const int k0 = kt << 6;
#pragma unroll
    for (int i = 0; i < 2; ++i) {
      int c = i * 512 + tid;
      int row = c >> 3, s = (c & 7) ^ r7;
      gload16(Ag + (size_t)row * K + k0 + s * 8, dst + (i * 512 + w * 64) * 16);
    }
  };
  auto stageB = [&](int kt, int buf) {           // 6 loads/thread
    char* dst = lds + 49152 + buf * 49152;
    const int k0 = kt << 6;
#pragma unroll
    for (int i = 0; i < 6; ++i) {
      int c = i * 512 + tid;
      int row = c >> 3, s = (c & 7) ^ r7;
      gload16(Bg + (size_t)row * K + k0 + s * 8, dst + (i * 512 + w * 64) * 16);
    }
  };

  const int NT = K >> 6;
  stageA(0, 0); stageA(1, 1); stageB(0, 0);
  asm volatile("s_waitcnt vmcnt(0)" ::: "memory");
  __builtin_amdgcn_s_barrier();
  asm volatile("" ::: "memory");

  f32x4 acc[4][6] = {};
  int abuf = 0, bbuf = 0;
  for (int t = 0; t < NT; ++t) {
    const char* Ab = lds + abuf * 16384;
    const char* Bb = lds + 49152 + bbuf * 49152;
    const bool doB = (t + 1 < NT);
    const bool doA = (t + 2 < NT);
    if (doB) stageB(t + 1, bbuf ^ 1);            // 6 loads
    if (doA) stageA(t + 2, (abuf + 2) % 3);      // 2 loads (stay in flight)

    bf16x8 af[4][2], bfr[6][2];
    auto rdA = [&](int mi, int ks) {
      return *(const bf16x8*)(Ab + ((wm * 64 + mi * 16 + l15) << 7) + (ks ? sw1 : sw0));
    };
    auto rdB = [&](int nj, int ks) {
      return *(const bf16x8*)(Bb + ((wn * 96 + nj * 16 + l15) << 7) + (ks ? sw1 : sw0));
    };

#pragma unroll
    for (int mi = 0; mi < 2; ++mi) { af[mi][0] = rdA(mi, 0); af[mi][1] = rdA(mi, 1); }
#pragma unroll
    for (int nj = 0; nj < 3; ++nj) { bfr[nj][0] = rdB(nj, 0); bfr[nj][1] = rdB(nj, 1); }
    __builtin_amdgcn_s_setprio(1);
#pragma unroll
    for (int mi = 0; mi < 2; ++mi)
#pragma unroll
      for (int nj = 0; nj < 3; ++nj) {
        acc[mi][nj] = mfma16(af[mi][0], bfr[nj][0], acc[mi][nj]);
        acc[mi][nj] = mfma16(af[mi][1], bfr[nj][1], acc[mi][nj]);
      }
    __builtin_amdgcn_s_setprio(0);

#pragma unroll
    for (int nj = 3; nj < 6; ++nj) { bfr[nj][0] = rdB(nj, 0); bfr[nj][1] = rdB(nj, 1); }
    __builtin_amdgcn_s_setprio(1);
#pragma unroll
    for (int mi = 0; mi < 2; ++mi)
#pragma unroll
      for (int nj = 3; nj < 6; ++nj) {
        acc[mi][nj] = mfma16(af[mi][0], bfr[nj][0], acc[mi][nj]);
        acc[mi][nj] = mfma16(af[mi][1], bfr[nj][1], acc[mi][nj]);
      }
    __builtin_amdgcn_s_setprio(0);

#pragma unroll
    for (int mi = 2; mi < 4; ++mi) { af[mi][0] = rdA(mi, 0); af[mi][1] = rdA(mi, 1); }
    __builtin_amdgcn_s_setprio(1);
#pragma unroll
    for (int mi = 2; mi < 4; ++mi)
#pragma unroll
      for (int nj = 3; nj < 6; ++nj) {
        acc[mi][nj] = mfma16(af[mi][0], bfr[nj][0], acc[mi][nj]);
        acc[mi][nj] = mfma16(af[mi][1], bfr[nj][1], acc[mi][nj]);
      }
    __builtin_amdgcn_s_setprio(0);

    __builtin_amdgcn_s_setprio(1);
#pragma unroll
    for (int mi = 2; mi < 4; ++mi)
#pragma unroll
      for (int nj = 0; nj < 3; ++nj) {
        acc[mi][nj] = mfma16(af[mi][0], bfr[nj][0], acc[mi][nj]);
        acc[mi][nj] = mfma16(af[mi][1], bfr[nj][1], acc[mi][nj]);
      }
    __builtin_amdgcn_s_setprio(0);

    if (doA)      asm volatile("s_waitcnt vmcnt(2)" ::: "memory");
    else          asm volatile("s_waitcnt vmcnt(0)" ::: "memory");
    __builtin_amdgcn_s_barrier();
    asm volatile("" ::: "memory");
    abuf = (abuf == 2) ? 0 : abuf + 1;
    bbuf ^= 1;
  }

#pragma unroll
  for (int mi = 0; mi < 4; ++mi) {
#pragma unroll
    for (int nj = 0; nj < 6; ++nj) {
      int row0 = bm * 128 + wm * 64 + mi * 16 + l4 * 4;
      int col  = bn * 384 + wn * 96 + nj * 16 + l15;
#pragma unroll
      for (int r = 0; r < 4; ++r)
        C[(size_t)(row0 + r) * N + col] = f2b(acc[mi][nj][r]);
    }
  }
}

// ---------- k_gemm2: out-proj GEMM (R10 proven, 128x256, f32 out) ----------
template<int BF16OUT>
__global__ __launch_bounds__(512, 2) void k_gemm2(const u16* __restrict__ A,
                                                  const u16* __restrict__ Bt,
                                                  void* __restrict__ Cv,
                                                  int M, int N, int K) {
  __shared__ __align__(16) char lds[147456];   // A: 3x16KB @0, B: 3x32KB @48K
  const int tid = threadIdx.x, w = tid >> 6, lane = tid & 63;
  const int l15 = lane & 15, l4 = lane >> 4;
  const int wm = w >> 2, wn = w & 3;
  const int nbx = gridDim.x;
  const int nwg = nbx * gridDim.y;
  const int id = blockIdx.y * nbx + blockIdx.x;
  const int qq = nwg >> 3;
  const int sid = (id & 7) * qq + (id >> 3);
  const int bn = sid % nbx, bm = sid / nbx;
  const u16* Ag = A + (size_t)bm * 128 * K;
  const u16* Bg = Bt + (size_t)bn * 256 * K;
  const int r7 = (tid >> 3) & 7;
  const int sw0 = ((0 + l4) ^ (l15 & 7)) * 16;
  const int sw1 = ((4 + l4) ^ (l15 & 7)) * 16;

  auto stageA = [&](int kt, int buf) {
    char* dst = lds + buf * 16384;
    const int k0 = kt << 6;
#pragma unroll
    for (int i = 0; i < 2; ++i) {
      int c = i * 512 + tid;
      int row = c >> 3, s = (c & 7) ^ r7;
      gload16(Ag + (size_t)row * K + k0 + s * 8, dst + (i * 512 + w * 64) * 16);
    }
  };
  auto stageBh = [&](int kt, int buf, int half) {
    char* dst = lds + 49152 + buf * 32768;
    const int k0 = kt << 6;
#pragma unroll
    for (int i = 0; i < 2; ++i) {
      int c = half * 1024 + i * 512 + tid;
      int row = c >> 3, s = (c & 7) ^ r7;
      gload16(Bg + (size_t)row * K + k0 + s * 8, dst + (half * 1024 + i * 512 + w * 64) * 16);
    }
  };

  const int NT = K >> 6;
  stageA(0, 0); stageBh(0, 0, 0); stageBh(0, 0, 1);
  stageA(1, 1); stageBh(1, 1, 0); stageBh(1, 1, 1);
  asm volatile("s_waitcnt vmcnt(6)" ::: "memory");
  __builtin_amdgcn_s_barrier();
  asm volatile("" ::: "memory");

  f32x4 acc[4][4] = {};
  int buf = 0, sbuf = 2;
  for (int t = 0; t < NT; ++t) {
    const char* Ab = lds + buf * 16384;
    const char* Bb = lds + 49152 + buf * 32768;
    const bool doStage = (t + 2 < NT);
    bf16x8 af[4][2], bfr[4][2];
    auto rdA = [&](int mi, int ks) {
      return *(const bf16x8*)(Ab + ((wm * 64 + mi * 16 + l15) << 7) + (ks ? sw1 : sw0));
    };
    auto rdB = [&](int nj, int ks) {
      return *(const bf16x8*)(Bb + ((wn * 64 + nj * 16 + l15) << 7) + (ks ? sw1 : sw0));
    };

#pragma unroll
    for (int mi = 0; mi < 2; ++mi) { af[mi][0] = rdA(mi, 0); af[mi][1] = rdA(mi, 1); }
#pragma unroll
    for (int nj = 0; nj < 2; ++nj) { bfr[nj][0] = rdB(nj, 0); bfr[nj][1] = rdB(nj, 1); }
    if (doStage) stageA(t + 2, sbuf);
    __builtin_amdgcn_s_setprio(1);
#pragma unroll
    for (int mi = 0; mi < 2; ++mi)
#pragma unroll
      for (int nj = 0; nj < 2; ++nj) {
        acc[mi][nj] = mfma16(af[mi][0], bfr[nj][0], acc[mi][nj]);
        acc[mi][nj] = mfma16(af[mi][1], bfr[nj][1], acc[mi][nj]);
      }
    __builtin_amdgcn_s_setprio(0);

#pragma unroll
    for (int nj = 2; nj < 4; ++nj) { bfr[nj][0] = rdB(nj, 0); bfr[nj][1] = rdB(nj, 1); }
    if (doStage) stageBh(t + 2, sbuf, 0);
    __builtin_amdgcn_s_setprio(1);
#pragma unroll
    for (int mi = 0; mi < 2; ++mi)
#pragma unroll
      for (int nj = 2; nj < 4; ++nj) {
        acc[mi][nj] = mfma16(af[mi][0], bfr[nj][0], acc[mi][nj]);
        acc[mi][nj] = mfma16(af[mi][1], bfr[nj][1], acc[mi][nj]);
      }
    __builtin_amdgcn_s_setprio(0);

#pragma unroll
    for (int mi = 2; mi < 4; ++mi) { af[mi][0] = rdA(mi, 0); af[mi][1] = rdA(mi, 1); }
    if (doStage) stageBh(t + 2, sbuf, 1);
    __builtin_amdgcn_s_setprio(1);
#pragma unroll
    for (int mi = 2; mi < 4; ++mi)
#pragma unroll
      for (int nj = 2; nj < 4; ++nj) {
        acc[mi][nj] = mfma16(af[mi][0], bfr[nj][0], acc[mi][nj]);
        acc[mi][nj] = mfma16(af[mi][1], bfr[nj][1], acc[mi][nj]);
      }
    __builtin_amdgcn_s_setprio(0);

    __builtin_amdgcn_s_setprio(1);
#pragma unroll
    for (int mi = 2; mi < 4; ++mi)
#pragma unroll
      for (int nj = 0; nj < 2; ++nj) {
        acc[mi][nj] = mfma16(af[mi][0], bfr[nj][0], acc[mi][nj]);
        acc[mi][nj] = mfma16(af[mi][1], bfr[nj][1], acc[mi][nj]);
      }
    __builtin_amdgcn_s_setprio(0);

    if (doStage) asm volatile("s_waitcnt vmcnt(6)" ::: "memory");
    else         asm volatile("s_waitcnt vmcnt(0)" ::: "memory");
    __builtin_amdgcn_s_barrier();
    asm volatile("" ::: "memory");
    buf = (buf == 2) ? 0 : buf + 1;
    sbuf = (sbuf == 2) ? 0 : sbuf + 1;
  }

#pragma unroll
  for (int mi = 0; mi < 4; ++mi) {
#pragma unroll
    for (int nj = 0; nj < 4; ++nj) {
      int row0 = bm * 128 + wm * 64 + mi * 16 + l4 * 4;
      int col  = bn * 256 + wn * 64 + nj * 16 + l15;
#pragma unroll
      for (int r = 0; r < 4; ++r) {
        float v = acc[mi][nj][r];
        if (BF16OUT) ((u16*)Cv)[(size_t)(row0 + r) * N + col] = f2b(v);
        else         ((float*)Cv)[(size_t)(row0 + r) * N + col] = v;
      }
    }
  }
}

// ---------- flash attention (R15: 80KB LDS, 2 blocks/CU, R7 body) ----------
__global__ __launch_bounds__(512, 2) void k_attn(const u16* __restrict__ qkv,
                                                 const u16* __restrict__ vt,
                                                 u16* __restrict__ aout) {
  __shared__ __align__(16) u16 Ks[2][64 * 128];    // [kv][d], XOR-swizzled rows
  __shared__ __align__(16) u16 Vs[2][128 * 64];    // V^T [d][kv], XOR-swizzled rows
  __shared__ __align__(16) u16 Ps[8 * 16 * 64];    // per-wave P, stride 64, shared A/B
  const int bid = blockIdx.x;                      // 256 blocks
  const int bh = bid & 31, pairi = bid >> 5;       // XCD = bid&7 = bh&7
  const int b = bh >> 4, h = bh & 15;
  const int qtA = pairi, qtB = 15 - pairi;
  const int tid = threadIdx.x, w = tid >> 6, lane = tid & 63;
  const int l15 = lane & 15, l4 = lane >> 4;

  bf16x8 qfA[4], qfB[4];
  {
    const u16* qpA = qkv + (size_t)(b * LSEQ + qtA * 128 + w * 16 + l15) * NQK + h * HD;
    const u16* qpB = qkv + (size_t)(b * LSEQ + qtB * 128 + w * 16 + l15) * NQK + h * HD;
#pragma unroll
    for (int ks = 0; ks < 4; ++ks) {
      qfA[ks] = *(const bf16x8*)(qpA + ks * 32 + l4 * 8);
      qfB[ks] = *(const bf16x8*)(qpB + ks * 32 + l4 * 8);
    }
  }

  f32x4 accA[8] = {}, accB[8] = {};
  float mA[4], lA[4], mB[4], lB[4];
#pragma unroll
  for (int r = 0; r < 4; ++r) { mA[r] = M0; lA[r] = 0.f; mB[r] = M0; lB[r] = 0.f; }

  const u16* kb  = qkv + (size_t)b * LSEQ * NQK + HIDDEN + h * HD;
  const u16* vtb = vt + (size_t)bh * HD * LSEQ;
  const int ntA = 2 * qtA + 2, ntB = 2 * qtB + 2;
  const int qbaseA = qtA * 128 + w * 16, qbaseB = qtB * 128 + w * 16;

  auto stage = [&](int t, int bf) {
    const int kv0 = t * 64;
    char* Kd = (char*)(&Ks[bf][0]);
    char* Vd = (char*)(&Vs[bf][0]);
#pragma unroll
    for (int p = 0; p < 2; ++p) {
      int cc = p * 512 + tid;
      int row = cc >> 4, sl = cc & 15;
      gload16(kb + (size_t)(kv0 + row) * NQK + ((sl ^ (row & 7)) * 8), Kd + (p * 512 + w * 64) * 16);
    }
#pragma unroll
    for (int p = 0; p < 2; ++p) {
      int cc = p * 512 + tid;
      int d = cc >> 3, sl = cc & 7;
      gload16(vtb + (size_t)d * LSEQ + kv0 + ((sl ^ (d & 7)) * 8), Vd + (p * 512 + w * 64) * 16);
    }
  };

  auto tileCompute = [&](const bf16x8 (&qf)[4], f32x4 (&acc_o)[8], float (&mrun)[4],
                         float (&lrun)[4], int qbase, int kv0,
                         const char* KsC, const char* VsC, u16* ps) {
    f32x4 s4[4] = {};
    __builtin_amdgcn_s_setprio(1);
#pragma unroll
    for (int ks = 0; ks < 4; ++ks) {
#pragma unroll
      for (int nj = 0; nj < 4; ++nj) {
        int row = nj * 16 + l15;
        int co = (ks * 64 + l4 * 16) ^ ((row & 7) << 4);
        bf16x8 kf = *(const bf16x8*)(KsC + row * 256 + co);
        s4[nj] = mfma16(qf[ks], kf, s4[nj]);
      }
    }
    __builtin_amdgcn_s_setprio(0);

    const int qrow0 = qbase + l4 * 4;
    float pv[4][4], lm[4];
    if (kv0 + 63 <= qbase) {                     // interior tile: no masking
#pragma unroll
      for (int r = 0; r < 4; ++r) {
        lm[r] = fmaxf(fmaxf(s4[0][r], s4[1][r]), fmaxf(s4[2][r], s4[3][r]));
#pragma unroll
        for (int nj = 0; nj < 4; ++nj) pv[nj][r] = s4[nj][r];
      }
    } else {
#pragma unroll
      for (int r = 0; r < 4; ++r) {
        float mx = -3e38f;
#pragma unroll
        for (int nj = 0; nj < 4; ++nj) {
          int kvcol = kv0 + nj * 16 + l15;
          float sv = (kvcol <= qrow0 + r) ? s4[nj][r] : -3e38f;
          pv[nj][r] = sv;
          mx = fmaxf(mx, sv);
        }
        lm[r] = mx;
      }
    }
    int over = (lm[0] > mrun[0]) | (lm[1] > mrun[1]) | (lm[2] > mrun[2]) | (lm[3] > mrun[3]);
    if (__builtin_expect(__any(over), 0)) {      // exact fallback (rare)
#pragma unroll
      for (int r = 0; r < 4; ++r) {
        float px = lm[r];
        px = fmaxf(px, __shfl_xor(px, 1));
        px = fmaxf(px, __shfl_xor(px, 2));
        px = fmaxf(px, __shfl_xor(px, 4));
        px = fmaxf(px, __shfl_xor(px, 8));
        if (px > mrun[r]) {
          float cf = exp2f(mrun[r] - px);
          mrun[r] = px;
          lrun[r] *= cf;
#pragma unroll
          for (int df = 0; df < 8; ++df) acc_o[df][r] *= cf;
        }
      }
    }
#pragma unroll
    for (int r = 0; r < 4; ++r) {
      float s = 0.f;
#pragma unroll
      for (int nj = 0; nj < 4; ++nj) {
        float e = exp2f(pv[nj][r] - mrun[r]);
        pv[nj][r] = e;
        s += e;
      }
      lrun[r] += s;                              // per-lane partial; reduced at end
    }
#pragma unroll
    for (int nj = 0; nj < 4; ++nj)
#pragma unroll
      for (int r = 0; r < 4; ++r)
        ps[(w * 16 + l4 * 4 + r) * 64 + nj * 16 + l15] = f2b(pv[nj][r]);

    bf16x8 pa[2];
#pragma unroll
    for (int ks2 = 0; ks2 < 2; ++ks2)
      pa[ks2] = *(const bf16x8*)(ps + (w * 16 + l15) * 64 + ks2 * 32 + l4 * 8);
    __builtin_amdgcn_s_setprio(1);
#pragma unroll
    for (int df = 0; df < 8; ++df) {
#pragma unroll
      for (int ks2 = 0; ks2 < 2; ++ks2) {
        int vrow = df * 16 + l15;
        int co = (ks2 * 64 + l4 * 16) ^ ((vrow & 7) << 4);
        bf16x8 bv = *(const bf16x8*)(VsC + vrow * 128 + co);
        acc_o[df] = mfma16(pa[ks2], bv, acc_o[df]);
      }
    }
    __builtin_amdgcn_s_setprio(0);
  };

  stage(0, 0);
  asm volatile("s_waitcnt vmcnt(0)" ::: "memory");
  __builtin_amdgcn_s_barrier();

  for (int t = 0; t < ntB; ++t) {
    const int buf = t & 1;
    if (t + 1 < ntB) stage(t + 1, buf ^ 1);      // prefetch next tile (other buffer)
    const int kv0 = t * 64;
    const char* KsC = (const char*)(&Ks[buf][0]);
    const char* VsC = (const char*)(&Vs[buf][0]);

    if ((t < ntA) && (kv0 <= qbaseA + 15))
      tileCompute(qfA, accA, mA, lA, qbaseA, kv0, KsC, VsC, &Ps[0]);
    if (kv0 <= qbaseB + 15)
      tileCompute(qfB, accB, mB, lB, qbaseB, kv0, KsC, VsC, &Ps[0]);

    asm volatile("s_waitcnt vmcnt(0)" ::: "memory");  // own prefetch landed
    __builtin_amdgcn_s_barrier();
  }

  // epilogue: reduce per-lane partial l across the 16-lane row group, O /= l
#pragma unroll
  for (int r = 0; r < 4; ++r) {
    float sA = lA[r];
    sA += __shfl_xor(sA, 1); sA += __shfl_xor(sA, 2);
    sA += __shfl_xor(sA, 4); sA += __shfl_xor(sA, 8);
    float sB = lB[r];
    sB += __shfl_xor(sB, 1); sB += __shfl_xor(sB, 2);
    sB += __shfl_xor(sB, 4); sB += __shfl_xor(sB, 8);
    float invA = 1.f / sA;
    float invB = 1.f / sB;
    u16* opA = aout + (size_t)(b * LSEQ + qtA * 128 + w * 16 + l4 * 4 + r) * HIDDEN + h * HD;
    u16* opB = aout + (size_t)(b * LSEQ + qtB * 128 + w * 16 + l4 * 4 + r) * HIDDEN + h * HD;
#pragma unroll
    for (int df = 0; df < 8; ++df) {
      opA[df * 16 + l15] = f2b(accA[df][r] * invA);
      opB[df * 16 + l15] = f2b(accB[df][r] * invB);
    }
  }
}

extern "C" void kernel_launch(void* const* d_in, const int* in_sizes, int n_in,
                              void* d_out, int out_size, void* d_ws, size_t ws_size,
                              hipStream_t stream) {
  const float* hidden = (const float*)d_in[0];
  // d_in[1] = attention_mask: causal, applied analytically in k_attn
  const int*   pos = (const int*)d_in[2];
  const float* Wq = (const float*)d_in[3];
  const float* Wk = (const float*)d_in[4];
  const float* Wv = (const float*)d_in[5];
  const float* Wo = (const float*)d_in[6];
  float* out = (float*)d_out;

  char* ws = (char*)d_ws;
  u16* hbf   = (u16*)ws;                                  // [4096][2048] bf16 (reused as attn_out)
  u16* WT    = (u16*)(ws + 16777216);                     // [6144][2048] bf16 (dead after QKV GEMM)
  u16* vt    = WT;                                        // [32][128][2048] bf16 V^T (aliases WT)
  u16* WoT   = (u16*)(ws + 16777216 + 25165824);          // [2048][2048] bf16
  u16* qkv   = (u16*)(ws + 50331648);                     // [4096][6144] bf16
  float* tab = (float*)(ws + 100663296);                  // [2048][64] {cos,sin}
  u16* aout  = hbf;

  int pstride = (in_sizes[2] == LSEQ) ? 1 : 2;            // int32 vs int64-as-int-pairs

  k_prep<<<dim3(32, 32, 13), 256, 0, stream>>>(Wq, Wk, Wv, Wo, WT, WoT, pos, pstride,
                                               tab, hidden, hbf);
  k_gemm3<<<dim3(16, 32), 512, 0, stream>>>(hbf, WT, qkv, 4096, 6144, 2048);
  k_rope_tv<<<18432, 256, 0, stream>>>(qkv, tab, vt);
  k_attn<<<256, 512, 0, stream>>>(qkv, vt, aout);
  k_gemm2<0><<<dim3(8, 32), 512, 0, stream>>>(aout, WoT, out, 4096, 2048, 2048);
}